// Round 7
// baseline (91.828 us; speedup 1.0000x reference)
//
#include <hip/hip_runtime.h>
#include <hip/hip_bf16.h>

typedef short bf16x8 __attribute__((ext_vector_type(8)));
typedef float f32x4  __attribute__((ext_vector_type(4)));

#define ZD      128      // feature dim
#define BT      128      // block tile (128x128, 64x64 per wave)
#define D2_CUT  60.0f    // exact-path cutoff: exp(-30)~9e-14
#define D2_TRIG 62.0f    // conservative trigger (margin > any bf16 dot err)

__device__ __forceinline__ unsigned short f2bf(float x) {
    unsigned u = __float_as_uint(x);
    u = (u + 0x7FFFu + ((u >> 16) & 1u)) >> 16;
    return (unsigned short)u;
}

// async global->LDS DMA, 16B per lane; LDS dest = wave-uniform base + lane*16
__device__ __forceinline__ void async_copy16(const unsigned short* g,
                                             unsigned short* l) {
    __builtin_amdgcn_global_load_lds(
        (const __attribute__((address_space(1))) unsigned int*)g,
        (__attribute__((address_space(3))) unsigned int*)l,
        16, 0, 0);
}

// ---------------------------------------------------------------------------
// Kernel A: 256 blocks x 32 rows. ||z_i||^2, per-32-row min, z->bf16.
// Block 0 / wave 2 additionally: class counts over all s, analytic diagonal,
// out[0] = diag*scale (pair atomics then add onto out -> 2-node graph).
// ---------------------------------------------------------------------------
__global__ __launch_bounds__(256) void dep_prep(
    const float* __restrict__ z, const int* __restrict__ s,
    float* __restrict__ sq, float* __restrict__ sqmin,
    unsigned short* __restrict__ zb, float* __restrict__ pvals,
    const float* __restrict__ norm, float* __restrict__ out, int N)
{
    __shared__ float part[32][33];
    const int tid  = threadIdx.x;
    const int wave = tid >> 6, lane = tid & 63;
    const int half = lane >> 5, c = lane & 31;
    const int r0   = blockIdx.x * 32;

    if (blockIdx.x == 0 && wave == 2) {
        int c0 = 0, c1 = 0, c2 = 0, c3 = 0;
        for (int it = lane; it < N / 4; it += 64) {
            int4 v = ((const int4*)s)[it];
            c0 += (v.x == 0) + (v.y == 0) + (v.z == 0) + (v.w == 0);
            c1 += (v.x == 1) + (v.y == 1) + (v.z == 1) + (v.w == 1);
            c2 += (v.x == 2) + (v.y == 2) + (v.z == 2) + (v.w == 2);
            c3 += (v.x == 3) + (v.y == 3) + (v.z == 3) + (v.w == 3);
        }
        #pragma unroll
        for (int off = 1; off < 64; off <<= 1) {
            c0 += __shfl_xor(c0, off, 64);
            c1 += __shfl_xor(c1, off, 64);
            c2 += __shfl_xor(c2, off, 64);
            c3 += __shfl_xor(c3, off, 64);
        }
        if (lane == 0) {
            const double n = (double)N;
            const double p0 = c0 / n, p1 = c1 / n, p2 = c2 / n, p3 = c3 / n;
            const double sump2 = p0*p0 + p1*p1 + p2*p2 + p3*p3;
            const double scale = (1.0 - exp(-1.0)) / ((double)norm[0] * n * n);
            pvals[0] = (float)p0; pvals[1] = (float)p1;
            pvals[2] = (float)p2; pvals[3] = (float)p3;
            pvals[4] = (float)sump2;
            pvals[5] = (float)scale;
            const double c2sum = (double)c0*c0 + (double)c1*c1
                               + (double)c2*c2 + (double)c3*c3;
            const double diag = n - c2sum / n;   // K_z[i,i] = 1 analytically
            out[0] = (float)(diag * scale);
        }
    }

    #pragma unroll
    for (int i = 0; i < 4; ++i) {
        const int rloc = wave * 8 + i * 2 + half;
        const int r    = r0 + rloc;
        float4 v = ((const float4*)z)[r * 32 + c];
        ushort4 u;
        u.x = f2bf(v.x); u.y = f2bf(v.y); u.z = f2bf(v.z); u.w = f2bf(v.w);
        ((ushort4*)zb)[r * 32 + c] = u;
        part[rloc][c] = v.x*v.x + v.y*v.y + v.z*v.z + v.w*v.w;
    }
    __syncthreads();

    if (wave == 0 && lane < 32) {
        float sum = 0.f;
        #pragma unroll
        for (int k = 0; k < 32; ++k) sum += part[lane][k];   // conflict-free
        sq[r0 + lane] = sum;
        float mn = sum;
        #pragma unroll
        for (int off = 1; off < 32; off <<= 1)               // lanes 0..31
            mn = fminf(mn, __shfl_xor(mn, off, 64));
        if (lane == 0) sqmin[blockIdx.x] = mn;
    }
}

// ---------------------------------------------------------------------------
// Kernel B: one block per 128x128 upper-triangle tile (2080 blocks).
// 32KB LDS: B panel ONLY (async DMA, global-side XOR swizzle -> verified
// 0-conflict read pattern). A fragments come straight from global with
// kc+1 double-buffered prefetch (16-VGPR transient, NOT a panel-sized
// live range -- R4's spill lesson); waves 0/1 and 2/3 share A rows via L1.
// 3 blocks/CU (launch_bounds(256,3)): staging drain of one block is
// covered by two others' compute. NO device-scope fences (R3's wall).
// Epilogue: conservative d2 bound; rare exact path adds local*scale onto
// out[0] (pre-set to diag*scale by prep).
// ---------------------------------------------------------------------------
__global__ __launch_bounds__(256, 3) void dep_pair(
    const unsigned short* __restrict__ zb, const float* __restrict__ sq,
    const float* __restrict__ sqmin, const int* __restrict__ s,
    const float* __restrict__ pvals, float* __restrict__ out, int T)
{
    __shared__ unsigned short Bpan[BT * ZD];   // 32KB

    const int tid  = threadIdx.x;
    const int wave = tid >> 6, lane = tid & 63;

    // block-uniform triangle map t -> (ti <= tj)
    const int t = blockIdx.x;
    #define TRI_BASE(x) ((x) * T - ((x) * ((x) - 1)) / 2)
    double disc = (2.0 * T + 1.0) * (2.0 * T + 1.0) - 8.0 * (double)t;
    int ti = (int)((2.0 * T + 1.0 - sqrt(disc)) * 0.5);
    if (ti < 0) ti = 0;
    if (ti > T - 1) ti = T - 1;
    while (ti + 1 < T && TRI_BASE(ti + 1) <= t) ++ti;
    while (ti > 0 && TRI_BASE(ti) > t) --ti;
    const int tj = ti + (t - TRI_BASE(ti));
    #undef TRI_BASE

    const int i0 = ti * BT, j0 = tj * BT;
    const int wi = wave >> 1, wj = wave & 1;
    const int l15 = lane & 15, quad = lane >> 4;

    // async stage B panel: each wave 8 DMAs of 1KB (4 rows each)
    {
        const unsigned short* gBp = zb + (size_t)j0 * ZD;
        const int rl = lane >> 4;           // row within 4-row group
        const int c  = lane & 15;           // dest 16B-chunk within row
        #pragma unroll
        for (int k = 0; k < 8; ++k) {
            const int r0i = (wave * 8 + k) * 4;       // wave-uniform
            const int row = r0i + rl;
            const int gch = c ^ (row & 15);           // global-side swizzle
            async_copy16(gBp + (size_t)row * ZD + (gch << 3),
                         Bpan + r0i * ZD);
        }
    }

    // A fragment bases + kc=0 prefetch (independent of LDS; overlaps drain)
    const unsigned short* abase[4];
    #pragma unroll
    for (int it = 0; it < 4; ++it)
        abase[it] = zb + (size_t)(i0 + wi * 64 + it * 16 + l15) * ZD + quad * 8;

    bf16x8 af[2][4];
    #pragma unroll
    for (int it = 0; it < 4; ++it)
        af[0][it] = *(const bf16x8*)(abase[it]);

    __syncthreads();   // vmcnt(0) drain; 2 other resident blocks overlap

    f32x4 accv[4][4];
    #pragma unroll
    for (int a = 0; a < 4; ++a)
        #pragma unroll
        for (int b = 0; b < 4; ++b)
            accv[a][b] = (f32x4){0.f, 0.f, 0.f, 0.f};

    #pragma unroll
    for (int kc = 0; kc < 4; ++kc) {
        if (kc < 3) {   // prefetch next kc's A fragments (transient regs)
            #pragma unroll
            for (int it = 0; it < 4; ++it)
                af[(kc + 1) & 1][it] =
                    *(const bf16x8*)(abase[it] + (kc + 1) * 32);
        }
        bf16x8 bfr[4];
        const int ch = (quad + 4 * kc) ^ l15;    // row&15 == l15
        #pragma unroll
        for (int jt = 0; jt < 4; ++jt) {
            const int row = wj * 64 + jt * 16 + l15;
            bfr[jt] = *(const bf16x8*)(Bpan + row * ZD + (ch << 3));
        }
        #pragma unroll
        for (int it = 0; it < 4; ++it)
            #pragma unroll
            for (int jt = 0; jt < 4; ++jt)
                accv[it][jt] = __builtin_amdgcn_mfma_f32_16x16x32_bf16(
                    af[kc & 1][it], bfr[jt], accv[it][jt], 0, 0, 0);
    }

    // ---- fast epilogue: wave-max of dots vs conservative d2 lower bound ----
    float m = -1e30f;
    #pragma unroll
    for (int it = 0; it < 4; ++it)
        #pragma unroll
        for (int jt = 0; jt < 4; ++jt) {
            const f32x4 v = accv[it][jt];
            m = fmaxf(m, fmaxf(fmaxf(v[0], v[1]), fmaxf(v[2], v[3])));
        }
    #pragma unroll
    for (int off = 1; off < 64; off <<= 1)
        m = fmaxf(m, __shfl_xor(m, off, 64));

    const int gA = (i0 >> 5) + wi * 2;        // 32-row sqmin groups
    const int gB = (j0 >> 5) + wj * 2;
    const float sminA = fminf(sqmin[gA], sqmin[gA + 1]);
    const float sminB = fminf(sqmin[gB], sqmin[gB + 1]);
    const float bound = sminA + sminB - 2.0f * m;

    if (bound < D2_TRIG) {   // wave-uniform; diag quadrants + ~1e-3 of rest
        const float p0 = pvals[0], p1 = pvals[1],
                    p2 = pvals[2], p3 = pvals[3];
        const float sump2 = pvals[4], scale = pvals[5];
        const float p[4] = {p0, p1, p2, p3};

        const int ibase = i0 + wi * 64, jbase = j0 + wj * 64;
        float sqj[4];
        #pragma unroll
        for (int jt = 0; jt < 4; ++jt) sqj[jt] = sq[jbase + jt * 16 + l15];

        float local = 0.f;
        #pragma unroll
        for (int it = 0; it < 4; ++it) {
            #pragma unroll
            for (int r = 0; r < 4; ++r) {
                const int i = ibase + it * 16 + quad * 4 + r;  // C/D row
                const float sqi = sq[i];
                #pragma unroll
                for (int jt = 0; jt < 4; ++jt) {
                    const int j = jbase + jt * 16 + l15;       // C/D col
                    float d2 = sqi + sqj[jt] - 2.0f * accv[it][jt][r];
                    d2 = fmaxf(d2, 0.0f);
                    if (d2 < D2_CUT && i != j) {
                        const int si = s[i], sj = s[j];
                        const float w = (si == sj ? 1.0f : 0.0f)
                                      - p[si] - p[sj] + sump2;
                        local += w * __expf(-0.5f * d2);
                    }
                }
            }
        }
        if (ti < tj) local *= 2.0f;   // off-diag tiles count both orders

        #pragma unroll
        for (int off = 32; off > 0; off >>= 1)
            local += __shfl_down(local, off, 64);
        if (lane == 0 && local != 0.0f)
            atomicAdd(out, local * scale);
    }
}

extern "C" void kernel_launch(void* const* d_in, const int* in_sizes, int n_in,
                              void* d_out, int out_size, void* d_ws, size_t ws_size,
                              hipStream_t stream)
{
    const float* z    = (const float*)d_in[0];
    const int*   s    = (const int*)d_in[1];
    const float* norm = (const float*)d_in[2];
    float* out = (float*)d_out;

    const int N = in_sizes[1];       // 8192
    const int T = N / BT;            // 64

    char* ws = (char*)d_ws;
    float*          pvals = (float*)ws;                       // 6 floats @0
    float*          sq    = (float*)(ws + 64);                // N floats
    float*          sqmin = (float*)(ws + 64 + (size_t)N * 4);        // N/32
    unsigned short* zb    = (unsigned short*)(ws + 64 + (size_t)N * 4
                                              + (size_t)(N / 32) * 4); // 16B-aligned

    dep_prep<<<N / 32, 256, 0, stream>>>(z, s, sq, sqmin, zb, pvals,
                                         norm, out, N);
    const int nblocks = T * (T + 1) / 2;   // 2080
    dep_pair<<<nblocks, 256, 0, stream>>>(zb, sq, sqmin, s, pvals, out, T);
}

// Round 8
// 85.857 us; speedup vs baseline: 1.0695x; 1.0695x over previous
//
#include <hip/hip_runtime.h>
#include <hip/hip_bf16.h>

typedef short bf16x8 __attribute__((ext_vector_type(8)));
typedef float f32x4  __attribute__((ext_vector_type(4)));

#define ZD      128      // feature dim
#define BT      128      // block tile (128x128, 64x64 per wave)
#define CH      4        // tj-chunk per block (A-panel reuse factor)
#define D2_CUT  60.0f    // exact-path cutoff: exp(-30)~9e-14
#define D2_TRIG 62.0f    // conservative trigger (margin > any bf16 dot err)

__device__ __forceinline__ unsigned short f2bf(float x) {
    unsigned u = __float_as_uint(x);
    u = (u + 0x7FFFu + ((u >> 16) & 1u)) >> 16;
    return (unsigned short)u;
}

// async global->LDS DMA, 16B per lane; LDS dest = wave-uniform base + lane*16
__device__ __forceinline__ void async_copy16(const unsigned short* g,
                                             unsigned short* l) {
    __builtin_amdgcn_global_load_lds(
        (const __attribute__((address_space(1))) unsigned int*)g,
        (__attribute__((address_space(3))) unsigned int*)l,
        16, 0, 0);
}

// ---------------------------------------------------------------------------
// Kernel A: 256 blocks x 32 rows. ||z_i||^2, per-32-row min, z->bf16.
// Block 0 / wave 2 additionally: class counts over all s, analytic diagonal,
// out[0] = diag*scale (pair atomics then add onto out -> 2-node graph).
// ---------------------------------------------------------------------------
__global__ __launch_bounds__(256) void dep_prep(
    const float* __restrict__ z, const int* __restrict__ s,
    float* __restrict__ sq, float* __restrict__ sqmin,
    unsigned short* __restrict__ zb, float* __restrict__ pvals,
    const float* __restrict__ norm, float* __restrict__ out, int N)
{
    __shared__ float part[32][33];
    const int tid  = threadIdx.x;
    const int wave = tid >> 6, lane = tid & 63;
    const int half = lane >> 5, c = lane & 31;
    const int r0   = blockIdx.x * 32;

    if (blockIdx.x == 0 && wave == 2) {
        int c0 = 0, c1 = 0, c2 = 0, c3 = 0;
        for (int it = lane; it < N / 4; it += 64) {
            int4 v = ((const int4*)s)[it];
            c0 += (v.x == 0) + (v.y == 0) + (v.z == 0) + (v.w == 0);
            c1 += (v.x == 1) + (v.y == 1) + (v.z == 1) + (v.w == 1);
            c2 += (v.x == 2) + (v.y == 2) + (v.z == 2) + (v.w == 2);
            c3 += (v.x == 3) + (v.y == 3) + (v.z == 3) + (v.w == 3);
        }
        #pragma unroll
        for (int off = 1; off < 64; off <<= 1) {
            c0 += __shfl_xor(c0, off, 64);
            c1 += __shfl_xor(c1, off, 64);
            c2 += __shfl_xor(c2, off, 64);
            c3 += __shfl_xor(c3, off, 64);
        }
        if (lane == 0) {
            const double n = (double)N;
            const double p0 = c0 / n, p1 = c1 / n, p2 = c2 / n, p3 = c3 / n;
            const double sump2 = p0*p0 + p1*p1 + p2*p2 + p3*p3;
            const double scale = (1.0 - exp(-1.0)) / ((double)norm[0] * n * n);
            pvals[0] = (float)p0; pvals[1] = (float)p1;
            pvals[2] = (float)p2; pvals[3] = (float)p3;
            pvals[4] = (float)sump2;
            pvals[5] = (float)scale;
            const double c2sum = (double)c0*c0 + (double)c1*c1
                               + (double)c2*c2 + (double)c3*c3;
            const double diag = n - c2sum / n;   // K_z[i,i] = 1 analytically
            out[0] = (float)(diag * scale);
        }
    }

    #pragma unroll
    for (int i = 0; i < 4; ++i) {
        const int rloc = wave * 8 + i * 2 + half;
        const int r    = r0 + rloc;
        float4 v = ((const float4*)z)[r * 32 + c];
        ushort4 u;
        u.x = f2bf(v.x); u.y = f2bf(v.y); u.z = f2bf(v.z); u.w = f2bf(v.w);
        ((ushort4*)zb)[r * 32 + c] = u;
        part[rloc][c] = v.x*v.x + v.y*v.y + v.z*v.z + v.w*v.w;
    }
    __syncthreads();

    if (wave == 0 && lane < 32) {
        float sum = 0.f;
        #pragma unroll
        for (int k = 0; k < 32; ++k) sum += part[lane][k];   // conflict-free
        sq[r0 + lane] = sum;
        float mn = sum;
        #pragma unroll
        for (int off = 1; off < 32; off <<= 1)               // lanes 0..31
            mn = fminf(mn, __shfl_xor(mn, off, 64));
        if (lane == 0) sqmin[blockIdx.x] = mn;
    }
}

// ---------------------------------------------------------------------------
// Kernel B: strip-mined upper triangle. Each block owns row ti's chunk of
// up to CH=4 consecutive tj tiles: A panel DMA-staged ONCE, B panels
// streamed one per tile (single buffer). Both panels in 64KB LDS with the
// R2/R5/R6-verified global-side XOR swizzle (0 bank conflicts); staging is
// async global_load_lds (no VGPR round-trip, R6-verified). B_{k+1}'s DMA
// is issued right after the post-compute barrier and the tile-k epilogue
// runs BEFORE the drain barrier, hiding part of the DMA drain. Per-tile
// staged bytes: 32KB (vs 64KB in R6); total L2 traffic 133->83MB.
// NO device-scope fences (R3), NO panel-sized register live range (R4),
// NO A-from-global in the MFMA loop (R7).
// ---------------------------------------------------------------------------
__global__ __launch_bounds__(256, 2) void dep_pair(
    const unsigned short* __restrict__ zb, const float* __restrict__ sq,
    const float* __restrict__ sqmin, const int* __restrict__ s,
    const float* __restrict__ pvals, float* __restrict__ out, int T)
{
    __shared__ unsigned short Apan[BT * ZD];   // 32KB
    __shared__ unsigned short Bpan[BT * ZD];   // 32KB

    const int tid  = threadIdx.x;
    const int wave = tid >> 6, lane = tid & 63;

    // strip map: block -> (ti, chunk); chunk covers tj = ti+CH*c .. min(...)
    int rem = blockIdx.x, ti = 0;
    for (; ti < T; ++ti) {                        // <=64 wave-uniform iters
        const int nc = (T - ti + CH - 1) / CH;
        if (rem < nc) break;
        rem -= nc;
    }
    const int tj0   = ti + rem * CH;
    const int tjend = min(tj0 + CH, T);

    const int i0  = ti * BT;
    const int wi  = wave >> 1, wj = wave & 1;
    const int l15 = lane & 15, quad = lane >> 4;
    const int rl  = lane >> 4, cch = lane & 15;   // DMA row-in-group / chunk

    // stage A panel (once) + first B panel: 8 DMAs of 1KB each per wave each
    {
        const unsigned short* gAp = zb + (size_t)i0 * ZD;
        const unsigned short* gBp = zb + (size_t)tj0 * BT * ZD;
        #pragma unroll
        for (int k = 0; k < 8; ++k) {
            const int r0i = (wave * 8 + k) * 4;        // wave-uniform
            const int row = r0i + rl;
            const int gch = cch ^ (row & 15);          // global-side swizzle
            const size_t go = (size_t)row * ZD + (gch << 3);
            async_copy16(gAp + go, Apan + r0i * ZD);
            async_copy16(gBp + go, Bpan + r0i * ZD);
        }
    }
    __syncthreads();   // vmcnt(0) drain; co-resident block overlaps

    for (int tj = tj0; tj < tjend; ++tj) {
        const int j0 = tj * BT;

        f32x4 accv[4][4];
        #pragma unroll
        for (int a = 0; a < 4; ++a)
            #pragma unroll
            for (int b = 0; b < 4; ++b)
                accv[a][b] = (f32x4){0.f, 0.f, 0.f, 0.f};

        #pragma unroll
        for (int kc = 0; kc < 4; ++kc) {
            bf16x8 af[4], bfr[4];
            const int ch = (quad + 4 * kc) ^ l15;    // row&15 == l15
            #pragma unroll
            for (int it = 0; it < 4; ++it) {
                const int row = wi * 64 + it * 16 + l15;
                af[it] = *(const bf16x8*)(Apan + row * ZD + (ch << 3));
            }
            #pragma unroll
            for (int jt = 0; jt < 4; ++jt) {
                const int row = wj * 64 + jt * 16 + l15;
                bfr[jt] = *(const bf16x8*)(Bpan + row * ZD + (ch << 3));
            }
            #pragma unroll
            for (int it = 0; it < 4; ++it)
                #pragma unroll
                for (int jt = 0; jt < 4; ++jt)
                    accv[it][jt] = __builtin_amdgcn_mfma_f32_16x16x32_bf16(
                        af[it], bfr[jt], accv[it][jt], 0, 0, 0);
        }

        __syncthreads();   // all waves done reading Bpan -> safe to restage

        // issue next B panel's DMA NOW; epilogue below hides its drain
        if (tj + 1 < tjend) {
            const unsigned short* gBp = zb + (size_t)(tj + 1) * BT * ZD;
            #pragma unroll
            for (int k = 0; k < 8; ++k) {
                const int r0i = (wave * 8 + k) * 4;
                const int row = r0i + rl;
                const int gch = cch ^ (row & 15);
                async_copy16(gBp + (size_t)row * ZD + (gch << 3),
                             Bpan + r0i * ZD);
            }
        }

        // ---- epilogue: wave-max of dots vs conservative d2 lower bound ----
        float m = -1e30f;
        #pragma unroll
        for (int it = 0; it < 4; ++it)
            #pragma unroll
            for (int jt = 0; jt < 4; ++jt) {
                const f32x4 v = accv[it][jt];
                m = fmaxf(m, fmaxf(fmaxf(v[0], v[1]), fmaxf(v[2], v[3])));
            }
        #pragma unroll
        for (int off = 1; off < 64; off <<= 1)
            m = fmaxf(m, __shfl_xor(m, off, 64));

        const int gA = (i0 >> 5) + wi * 2;        // 32-row sqmin groups
        const int gB = (j0 >> 5) + wj * 2;
        const float sminA = fminf(sqmin[gA], sqmin[gA + 1]);
        const float sminB = fminf(sqmin[gB], sqmin[gB + 1]);
        const float bound = sminA + sminB - 2.0f * m;

        if (bound < D2_TRIG) {   // wave-uniform; diag quadrants + ~1e-3
            const float p0 = pvals[0], p1 = pvals[1],
                        p2 = pvals[2], p3 = pvals[3];
            const float sump2 = pvals[4], scale = pvals[5];
            const float p[4] = {p0, p1, p2, p3};

            const int ibase = i0 + wi * 64, jbase = j0 + wj * 64;
            float sqj[4];
            #pragma unroll
            for (int jt = 0; jt < 4; ++jt)
                sqj[jt] = sq[jbase + jt * 16 + l15];

            float local = 0.f;
            #pragma unroll
            for (int it = 0; it < 4; ++it) {
                #pragma unroll
                for (int r = 0; r < 4; ++r) {
                    const int i = ibase + it * 16 + quad * 4 + r;  // C/D row
                    const float sqi = sq[i];
                    #pragma unroll
                    for (int jt = 0; jt < 4; ++jt) {
                        const int j = jbase + jt * 16 + l15;       // C/D col
                        float d2 = sqi + sqj[jt] - 2.0f * accv[it][jt][r];
                        d2 = fmaxf(d2, 0.0f);
                        if (d2 < D2_CUT && i != j) {
                            const int si = s[i], sj = s[j];
                            const float w = (si == sj ? 1.0f : 0.0f)
                                          - p[si] - p[sj] + sump2;
                            local += w * __expf(-0.5f * d2);
                        }
                    }
                }
            }
            if (ti < tj) local *= 2.0f;   // off-diag tiles count both orders

            #pragma unroll
            for (int off = 32; off > 0; off >>= 1)
                local += __shfl_down(local, off, 64);
            if (lane == 0 && local != 0.0f)
                atomicAdd(out, local * scale);
        }

        if (tj + 1 < tjend) __syncthreads();   // drain B_{k+1} before compute
    }
}

extern "C" void kernel_launch(void* const* d_in, const int* in_sizes, int n_in,
                              void* d_out, int out_size, void* d_ws, size_t ws_size,
                              hipStream_t stream)
{
    const float* z    = (const float*)d_in[0];
    const int*   s    = (const int*)d_in[1];
    const float* norm = (const float*)d_in[2];
    float* out = (float*)d_out;

    const int N = in_sizes[1];       // 8192
    const int T = N / BT;            // 64

    char* ws = (char*)d_ws;
    float*          pvals = (float*)ws;                       // 6 floats @0
    float*          sq    = (float*)(ws + 64);                // N floats
    float*          sqmin = (float*)(ws + 64 + (size_t)N * 4);        // N/32
    unsigned short* zb    = (unsigned short*)(ws + 64 + (size_t)N * 4
                                              + (size_t)(N / 32) * 4); // 16B-aligned

    dep_prep<<<N / 32, 256, 0, stream>>>(z, s, sq, sqmin, zb, pvals,
                                         norm, out, N);

    int nblocks = 0;                 // sum of per-row chunk counts = 544
    for (int t = 0; t < T; ++t) nblocks += (T - t + CH - 1) / CH;
    dep_pair<<<nblocks, 256, 0, stream>>>(zb, sq, sqmin, s, pvals, out, T);
}

// Round 9
// 78.161 us; speedup vs baseline: 1.1749x; 1.0985x over previous
//
#include <hip/hip_runtime.h>
#include <hip/hip_bf16.h>

typedef float f32x4 __attribute__((ext_vector_type(4)));

#define ZD      128      // feature dim (bytes per fp8 row, too)
#define BT      128      // block tile (128x128, 64x64 per wave)
#define D2_CUT  60.0f    // exact-path cutoff: exp(-30)~9e-14
#define D2_TRIG 70.0f    // trigger: fp8 dot err <= ~+-3 on d2 => skip implies
                         // true d2 >= 70-6 > D2_CUT (12-sigma data margin)

// async global->LDS DMA, 16B per lane; LDS dest = wave-uniform base + lane*16
__device__ __forceinline__ void async_copy16(const unsigned char* g,
                                             unsigned char* l) {
    __builtin_amdgcn_global_load_lds(
        (const __attribute__((address_space(1))) unsigned int*)g,
        (__attribute__((address_space(3))) unsigned int*)l,
        16, 0, 0);
}

// ---------------------------------------------------------------------------
// Kernel A: 256 blocks x 32 rows. ||z_i||^2 (fp32 exact), per-32-row min,
// z -> fp8 e4m3 (HW cvt_pk, 4 elems/lane/row). Block 0 / wave 2: class
// counts over all s, analytic diagonal, out[0] = diag*scale.
// ---------------------------------------------------------------------------
__global__ __launch_bounds__(256) void dep_prep(
    const float* __restrict__ z, const int* __restrict__ s,
    float* __restrict__ sq, float* __restrict__ sqmin,
    unsigned char* __restrict__ zb8, float* __restrict__ pvals,
    const float* __restrict__ norm, float* __restrict__ out, int N)
{
    __shared__ float part[32][33];
    const int tid  = threadIdx.x;
    const int wave = tid >> 6, lane = tid & 63;
    const int half = lane >> 5, c = lane & 31;
    const int r0   = blockIdx.x * 32;

    if (blockIdx.x == 0 && wave == 2) {
        int c0 = 0, c1 = 0, c2 = 0, c3 = 0;
        for (int it = lane; it < N / 4; it += 64) {
            int4 v = ((const int4*)s)[it];
            c0 += (v.x == 0) + (v.y == 0) + (v.z == 0) + (v.w == 0);
            c1 += (v.x == 1) + (v.y == 1) + (v.z == 1) + (v.w == 1);
            c2 += (v.x == 2) + (v.y == 2) + (v.z == 2) + (v.w == 2);
            c3 += (v.x == 3) + (v.y == 3) + (v.z == 3) + (v.w == 3);
        }
        #pragma unroll
        for (int off = 1; off < 64; off <<= 1) {
            c0 += __shfl_xor(c0, off, 64);
            c1 += __shfl_xor(c1, off, 64);
            c2 += __shfl_xor(c2, off, 64);
            c3 += __shfl_xor(c3, off, 64);
        }
        if (lane == 0) {
            const double n = (double)N;
            const double p0 = c0 / n, p1 = c1 / n, p2 = c2 / n, p3 = c3 / n;
            const double sump2 = p0*p0 + p1*p1 + p2*p2 + p3*p3;
            const double scale = (1.0 - exp(-1.0)) / ((double)norm[0] * n * n);
            pvals[0] = (float)p0; pvals[1] = (float)p1;
            pvals[2] = (float)p2; pvals[3] = (float)p3;
            pvals[4] = (float)sump2;
            pvals[5] = (float)scale;
            const double c2sum = (double)c0*c0 + (double)c1*c1
                               + (double)c2*c2 + (double)c3*c3;
            const double diag = n - c2sum / n;   // K_z[i,i] = 1 analytically
            out[0] = (float)(diag * scale);
        }
    }

    #pragma unroll
    for (int i = 0; i < 4; ++i) {
        const int rloc = wave * 8 + i * 2 + half;
        const int r    = r0 + rloc;
        float4 v = ((const float4*)z)[r * 32 + c];
        int pk = __builtin_amdgcn_cvt_pk_fp8_f32(v.x, v.y, 0, false);
        pk     = __builtin_amdgcn_cvt_pk_fp8_f32(v.z, v.w, pk, true);
        ((unsigned int*)zb8)[r * 32 + c] = (unsigned int)pk;
        part[rloc][c] = v.x*v.x + v.y*v.y + v.z*v.z + v.w*v.w;
    }
    __syncthreads();

    if (wave == 0 && lane < 32) {
        float sum = 0.f;
        #pragma unroll
        for (int k = 0; k < 32; ++k) sum += part[lane][k];   // conflict-free
        sq[r0 + lane] = sum;
        float mn = sum;
        #pragma unroll
        for (int off = 1; off < 32; off <<= 1)               // lanes 0..31
            mn = fminf(mn, __shfl_xor(mn, off, 64));
        if (lane == 0) sqmin[blockIdx.x] = mn;
    }
}

// ---------------------------------------------------------------------------
// Kernel B: one block per 128x128 upper-triangle tile (2080 blocks) — R6's
// proven schedule, fp8 panels. A+B = 32KB LDS -> 4 blocks/CU (16 waves/CU):
// each DMA drain covered by 3 other blocks' compute; staged traffic halves
// (133->66MB). Global-side XOR swizzle at 16B-chunk granularity
// (ch ^= row&7): fragment ds_read_b64 is 4-way bank-aliased (1.58x, ok).
// mfma_f32_16x16x32_fp8_fp8: same lane->A/B element mapping as bf16
// (8 elems/lane, k=quad*8+j), 1 byte/elem. Epilogue: conservative d2
// bound (TRIG widened for fp8 dot err); rare exact path adds local*scale
// onto out[0] (pre-set to diag*scale by prep).
// ---------------------------------------------------------------------------
__global__ __launch_bounds__(256, 4) void dep_pair(
    const unsigned char* __restrict__ zb8, const float* __restrict__ sq,
    const float* __restrict__ sqmin, const int* __restrict__ s,
    const float* __restrict__ pvals, float* __restrict__ out, int T)
{
    __shared__ unsigned char Apan[BT * ZD];   // 16KB
    __shared__ unsigned char Bpan[BT * ZD];   // 16KB

    const int tid  = threadIdx.x;
    const int wave = tid >> 6, lane = tid & 63;

    // block-uniform triangle map t -> (ti <= tj)
    const int t = blockIdx.x;
    #define TRI_BASE(x) ((x) * T - ((x) * ((x) - 1)) / 2)
    double disc = (2.0 * T + 1.0) * (2.0 * T + 1.0) - 8.0 * (double)t;
    int ti = (int)((2.0 * T + 1.0 - sqrt(disc)) * 0.5);
    if (ti < 0) ti = 0;
    if (ti > T - 1) ti = T - 1;
    while (ti + 1 < T && TRI_BASE(ti + 1) <= t) ++ti;
    while (ti > 0 && TRI_BASE(ti) > t) --ti;
    const int tj = ti + (t - TRI_BASE(ti));
    #undef TRI_BASE

    const int i0 = ti * BT, j0 = tj * BT;
    const int wi = wave >> 1, wj = wave & 1;
    const int l15 = lane & 15, quad = lane >> 4;

    // async stage both panels: per wave 4+4 DMAs of 1KB (8 rows each).
    // LDS[row][c] = G[row][c ^ (row&7)]  (global-side swizzle; base uniform)
    {
        const unsigned char* gAp = zb8 + (size_t)i0 * ZD;
        const unsigned char* gBp = zb8 + (size_t)j0 * ZD;
        const int rl  = lane >> 3;          // row within 8-row group (0..7)
        const int cch = lane & 7;           // dest 16B-chunk within row
        const int gch = cch ^ rl;           // source chunk (row&7 == rl)
        #pragma unroll
        for (int k = 0; k < 4; ++k) {
            const int r0i = (wave * 4 + k) * 8;        // wave-uniform
            const size_t go = (size_t)(r0i + rl) * ZD + (gch << 4);
            async_copy16(gAp + go, Apan + r0i * ZD);
            async_copy16(gBp + go, Bpan + r0i * ZD);
        }
    }
    __syncthreads();   // vmcnt(0) drain; 3 co-resident blocks overlap

    f32x4 accv[4][4];
    #pragma unroll
    for (int a = 0; a < 4; ++a)
        #pragma unroll
        for (int b = 0; b < 4; ++b)
            accv[a][b] = (f32x4){0.f, 0.f, 0.f, 0.f};

    const int sub = (quad & 1) * 8;         // 8B half within 16B chunk
    #pragma unroll
    for (int kc = 0; kc < 4; ++kc) {
        long af[4], bfr[4];
        // orig chunk = kc*2 + quad/2; row&7 == l15&7 for all fragment rows
        const int ch = (kc * 2 + (quad >> 1)) ^ (l15 & 7);
        #pragma unroll
        for (int it = 0; it < 4; ++it) {
            const int row = wi * 64 + it * 16 + l15;
            af[it] = *(const long*)(Apan + row * ZD + (ch << 4) + sub);
        }
        #pragma unroll
        for (int jt = 0; jt < 4; ++jt) {
            const int row = wj * 64 + jt * 16 + l15;
            bfr[jt] = *(const long*)(Bpan + row * ZD + (ch << 4) + sub);
        }
        #pragma unroll
        for (int it = 0; it < 4; ++it)
            #pragma unroll
            for (int jt = 0; jt < 4; ++jt)
                accv[it][jt] = __builtin_amdgcn_mfma_f32_16x16x32_fp8_fp8(
                    af[it], bfr[jt], accv[it][jt], 0, 0, 0);
    }

    // ---- fast epilogue: wave-max of dots vs conservative d2 lower bound ----
    float m = -1e30f;
    #pragma unroll
    for (int it = 0; it < 4; ++it)
        #pragma unroll
        for (int jt = 0; jt < 4; ++jt) {
            const f32x4 v = accv[it][jt];
            m = fmaxf(m, fmaxf(fmaxf(v[0], v[1]), fmaxf(v[2], v[3])));
        }
    #pragma unroll
    for (int off = 1; off < 64; off <<= 1)
        m = fmaxf(m, __shfl_xor(m, off, 64));

    const int gA = (i0 >> 5) + wi * 2;        // 32-row sqmin groups
    const int gB = (j0 >> 5) + wj * 2;
    const float sminA = fminf(sqmin[gA], sqmin[gA + 1]);
    const float sminB = fminf(sqmin[gB], sqmin[gB + 1]);
    const float bound = sminA + sminB - 2.0f * m;

    if (bound < D2_TRIG) {   // wave-uniform; diag quadrants + rare triggers
        const float p0 = pvals[0], p1 = pvals[1],
                    p2 = pvals[2], p3 = pvals[3];
        const float sump2 = pvals[4], scale = pvals[5];
        const float p[4] = {p0, p1, p2, p3};

        const int ibase = i0 + wi * 64, jbase = j0 + wj * 64;
        float sqj[4];
        #pragma unroll
        for (int jt = 0; jt < 4; ++jt) sqj[jt] = sq[jbase + jt * 16 + l15];

        float local = 0.f;
        #pragma unroll
        for (int it = 0; it < 4; ++it) {
            #pragma unroll
            for (int r = 0; r < 4; ++r) {
                const int i = ibase + it * 16 + quad * 4 + r;  // C/D row
                const float sqi = sq[i];
                #pragma unroll
                for (int jt = 0; jt < 4; ++jt) {
                    const int j = jbase + jt * 16 + l15;       // C/D col
                    float d2 = sqi + sqj[jt] - 2.0f * accv[it][jt][r];
                    d2 = fmaxf(d2, 0.0f);
                    if (d2 < D2_CUT && i != j) {
                        const int si = s[i], sj = s[j];
                        const float w = (si == sj ? 1.0f : 0.0f)
                                      - p[si] - p[sj] + sump2;
                        local += w * __expf(-0.5f * d2);
                    }
                }
            }
        }
        if (ti < tj) local *= 2.0f;   // off-diag tiles count both orders

        #pragma unroll
        for (int off = 32; off > 0; off >>= 1)
            local += __shfl_down(local, off, 64);
        if (lane == 0 && local != 0.0f)
            atomicAdd(out, local * scale);
    }
}

extern "C" void kernel_launch(void* const* d_in, const int* in_sizes, int n_in,
                              void* d_out, int out_size, void* d_ws, size_t ws_size,
                              hipStream_t stream)
{
    const float* z    = (const float*)d_in[0];
    const int*   s    = (const int*)d_in[1];
    const float* norm = (const float*)d_in[2];
    float* out = (float*)d_out;

    const int N = in_sizes[1];       // 8192
    const int T = N / BT;            // 64

    char* ws = (char*)d_ws;
    float*         pvals = (float*)ws;                        // 6 floats @0
    float*         sq    = (float*)(ws + 64);                 // N floats
    float*         sqmin = (float*)(ws + 64 + (size_t)N * 4); // N/32
    unsigned char* zb8   = (unsigned char*)(ws + 64 + (size_t)N * 4
                                            + (size_t)(N / 32) * 4); // 16B-aligned

    dep_prep<<<N / 32, 256, 0, stream>>>(z, s, sq, sqmin, zb8, pvals,
                                         norm, out, N);
    const int nblocks = T * (T + 1) / 2;   // 2080
    dep_pair<<<nblocks, 256, 0, stream>>>(zb8, sq, sqmin, s, pvals, out, T);
}